// Round 1
// baseline (954.323 us; speedup 1.0000x reference)
//
#include <hip/hip_runtime.h>

#define N_NODES 50000

// ---------------------------------------------------------------------------
// Stage 1: sum[dst] += edge_feats ; deg[dst] += 1
// thread per (edge, d): coalesced edge_feats read, scatter-add via atomics.
// ---------------------------------------------------------------------------
__global__ __launch_bounds__(256) void k_scatter_feats(
    const float* __restrict__ ef, const int* __restrict__ dst,
    float* __restrict__ sum, float* __restrict__ deg, int total)
{
    int t = blockIdx.x * 256 + threadIdx.x;
    if (t >= total) return;
    int e = t >> 5;
    int d = t & 31;
    int n = dst[e];
    atomicAdd(sum + (size_t)n * 32 + d, ef[t]);
    if (d == 0) atomicAdd(deg + n, 1.0f);
}

// ---------------------------------------------------------------------------
// Stage 2: mean = sum / max(deg,1)   (in place: sum becomes node_mean)
// ---------------------------------------------------------------------------
__global__ __launch_bounds__(256) void k_mean(
    float* __restrict__ sum, const float* __restrict__ deg, int total)
{
    int t = blockIdx.x * 256 + threadIdx.x;
    if (t >= total) return;
    float dg = deg[t >> 5];
    sum[t] = sum[t] / fmaxf(dg, 1.0f);
}

// ---------------------------------------------------------------------------
// Stage 3: h[dst] += mean[src]   (gather 128B rows from LLC, scatter atomics)
// ---------------------------------------------------------------------------
__global__ __launch_bounds__(256) void k_scatter_mean(
    const float* __restrict__ mean, const int* __restrict__ src,
    const int* __restrict__ dst, float* __restrict__ h, int total)
{
    int t = blockIdx.x * 256 + threadIdx.x;
    if (t >= total) return;
    int e = t >> 5;
    int d = t & 31;
    int s = src[e];
    int n = dst[e];
    atomicAdd(h + (size_t)n * 32 + d, mean[(size_t)s * 32 + d]);
}

// ---------------------------------------------------------------------------
// Stage 4: out[e] = (0.5*(h[src]+h[dst])) @ W^T + b
// 32 edges per block. Phase 1 stages edge_h into LDS (stride 36: float4-
// aligned, breaks power-of-2 bank aliasing). Phase 2: thread (j=t&31) holds
// W row j in registers; edge_h LDS reads are wave-broadcast; output stores
// are contiguous 128B runs per 32 lanes (fully coalesced).
// ---------------------------------------------------------------------------
__global__ __launch_bounds__(256) void k_edge_out(
    const float* __restrict__ h, const int* __restrict__ src,
    const int* __restrict__ dst, const float* __restrict__ W,
    const float* __restrict__ b, float* __restrict__ out, int E)
{
    __shared__ float sh[32][36];
    const int t  = threadIdx.x;
    const int e0 = blockIdx.x * 32;

    // ---- phase 1: edge_h -> LDS (256 threads = 32 edges x 8 float4 chunks)
    {
        int e  = t >> 3;          // 0..31
        int d4 = (t & 7) << 2;    // 0,4,...,28
        int ge = e0 + e;
        float4 v = make_float4(0.f, 0.f, 0.f, 0.f);
        if (ge < E) {
            int s = src[ge];
            int n = dst[ge];
            float4 a = *(const float4*)(h + (size_t)s * 32 + d4);
            float4 c = *(const float4*)(h + (size_t)n * 32 + d4);
            v.x = 0.5f * (a.x + c.x);
            v.y = 0.5f * (a.y + c.y);
            v.z = 0.5f * (a.z + c.z);
            v.w = 0.5f * (a.w + c.w);
        }
        *(float4*)(&sh[e][d4]) = v;   // (e*36+d4)*4 is 16B aligned
    }
    __syncthreads();

    // ---- phase 2: thread computes out[e0+eb+8q][j] for q=0..3
    const int j  = t & 31;   // output feature
    const int eb = t >> 5;   // 0..7

    float w[32];
#pragma unroll
    for (int k = 0; k < 8; ++k) {
        float4 wv = *(const float4*)(W + j * 32 + k * 4);
        w[k * 4 + 0] = wv.x;
        w[k * 4 + 1] = wv.y;
        w[k * 4 + 2] = wv.z;
        w[k * 4 + 3] = wv.w;
    }
    float bj = b[j];
    float a0 = bj, a1 = bj, a2 = bj, a3 = bj;
#pragma unroll
    for (int d = 0; d < 32; ++d) {
        float wd = w[d];
        a0 += sh[eb +  0][d] * wd;
        a1 += sh[eb +  8][d] * wd;
        a2 += sh[eb + 16][d] * wd;
        a3 += sh[eb + 24][d] * wd;
    }
    if (e0 + eb +  0 < E) out[(size_t)(e0 + eb +  0) * 32 + j] = a0;
    if (e0 + eb +  8 < E) out[(size_t)(e0 + eb +  8) * 32 + j] = a1;
    if (e0 + eb + 16 < E) out[(size_t)(e0 + eb + 16) * 32 + j] = a2;
    if (e0 + eb + 24 < E) out[(size_t)(e0 + eb + 24) * 32 + j] = a3;
}

extern "C" void kernel_launch(void* const* d_in, const int* in_sizes, int n_in,
                              void* d_out, int out_size, void* d_ws, size_t ws_size,
                              hipStream_t stream)
{
    const float* ef  = (const float*)d_in[0];
    const int*   src = (const int*)d_in[1];
    const int*   dst = (const int*)d_in[2];
    const float* W   = (const float*)d_in[3];
    const float* b   = (const float*)d_in[4];
    float*       out = (float*)d_out;
    const int E = in_sizes[1];

    const size_t NF = (size_t)N_NODES * 32;
    float* sum = (float*)d_ws;        // NF floats; becomes node_mean in place
    float* h   = sum + NF;            // NF floats
    float* deg = h + NF;              // N_NODES floats

    // zero the accumulators (ws is poisoned 0xAA before every launch)
    hipMemsetAsync(d_ws, 0, (2 * NF + N_NODES) * sizeof(float), stream);

    const int total  = E * 32;                    // 51.2M, fits int
    const int blocks = (total + 255) / 256;

    k_scatter_feats<<<blocks, 256, 0, stream>>>(ef, dst, sum, deg, total);

    const int ntot = (int)NF;
    k_mean<<<(ntot + 255) / 256, 256, 0, stream>>>(sum, deg, ntot);

    k_scatter_mean<<<blocks, 256, 0, stream>>>(sum, src, dst, h, total);

    const int eblocks = (E + 31) / 32;
    k_edge_out<<<eblocks, 256, 0, stream>>>(h, src, dst, W, b, out, E);
}

// Round 2
// 813.184 us; speedup vs baseline: 1.1736x; 1.1736x over previous
//
#include <hip/hip_runtime.h>

#define N_NODES 50000
#define SCAN_T 1024

// ---------------------------------------------------------------------------
// CSR build, step 1: histogram of dst. cnt is zeroed by memset beforehand.
// 1.6M int atomics on a 200KB L2-resident table — fast.
// ---------------------------------------------------------------------------
__global__ __launch_bounds__(256) void k_hist(
    const int* __restrict__ dst, int* __restrict__ cnt, int E)
{
    int e = blockIdx.x * 256 + threadIdx.x;
    if (e < E) atomicAdd(&cnt[dst[e]], 1);
}

// ---------------------------------------------------------------------------
// CSR build, step 2: exclusive scan of cnt[0..N) -> off[0..N], cursor copy.
// Single block of 1024 threads, each handles ceil(N/1024)=49 elements;
// Hillis-Steele scan of the 1024 partials in LDS.
// ---------------------------------------------------------------------------
__global__ __launch_bounds__(SCAN_T) void k_scan(
    const int* __restrict__ cnt, int* __restrict__ off,
    int* __restrict__ cur, int E)
{
    __shared__ int part[SCAN_T];
    const int tid = threadIdx.x;
    const int C = (N_NODES + SCAN_T - 1) / SCAN_T;
    const int beg = tid * C;
    const int end = min(beg + C, N_NODES);
    int local = 0;
    for (int i = beg; i < end; ++i) local += cnt[i];
    part[tid] = local;
    __syncthreads();
    for (int s = 1; s < SCAN_T; s <<= 1) {
        int add = (tid >= s) ? part[tid - s] : 0;
        __syncthreads();
        part[tid] += add;
        __syncthreads();
    }
    int p = part[tid] - local;   // exclusive prefix of this thread's chunk
    for (int i = beg; i < end; ++i) {
        int c = cnt[i];
        off[i] = p;
        cur[i] = p;
        p += c;
    }
    if (tid == 0) off[N_NODES] = E;
}

// ---------------------------------------------------------------------------
// CSR build, step 3: fill edge-id lists. cursor atomics only (int, L2-hot).
// ---------------------------------------------------------------------------
__global__ __launch_bounds__(256) void k_fill(
    const int* __restrict__ dst, int* __restrict__ cur,
    int* __restrict__ csr, int E)
{
    int e = blockIdx.x * 256 + threadIdx.x;
    if (e >= E) return;
    int p = atomicAdd(&cur[dst[e]], 1);
    csr[p] = e;
}

// ---------------------------------------------------------------------------
// Stage 1+2: mean[n] = (sum of ef rows of n's in-edges) / max(deg,1).
// 32 lanes per node (lane = feature), 8 nodes per 256-block. Each edge's
// row read is a contiguous 128B chunk (coalesced across the 32 lanes).
// Unroll x2 keeps two loads in flight.
// ---------------------------------------------------------------------------
__global__ __launch_bounds__(256) void k_node_mean(
    const float* __restrict__ ef, const int* __restrict__ csr,
    const int* __restrict__ off, float* __restrict__ mean)
{
    int n = blockIdx.x * 8 + (threadIdx.x >> 5);
    if (n >= N_NODES) return;
    int d = threadIdx.x & 31;
    int beg = off[n], end = off[n + 1];
    float a0 = 0.f, a1 = 0.f;
    int i = beg;
    for (; i + 2 <= end; i += 2) {
        int e0 = csr[i];
        int e1 = csr[i + 1];
        a0 += ef[(size_t)e0 * 32 + d];
        a1 += ef[(size_t)e1 * 32 + d];
    }
    if (i < end) a0 += ef[(size_t)csr[i] * 32 + d];
    float s = a0 + a1;
    mean[(size_t)n * 32 + d] = s / fmaxf((float)(end - beg), 1.0f);
}

// ---------------------------------------------------------------------------
// Stage 3: h[n] = sum over in-edges e of mean[src[e]]. Gathers from the
// 6.4MB L2/LLC-resident mean table.
// ---------------------------------------------------------------------------
__global__ __launch_bounds__(256) void k_node_h(
    const float* __restrict__ mean, const int* __restrict__ src,
    const int* __restrict__ csr, const int* __restrict__ off,
    float* __restrict__ h)
{
    int n = blockIdx.x * 8 + (threadIdx.x >> 5);
    if (n >= N_NODES) return;
    int d = threadIdx.x & 31;
    int beg = off[n], end = off[n + 1];
    float a0 = 0.f, a1 = 0.f;
    int i = beg;
    for (; i + 2 <= end; i += 2) {
        int s0 = src[csr[i]];
        int s1 = src[csr[i + 1]];
        a0 += mean[(size_t)s0 * 32 + d];
        a1 += mean[(size_t)s1 * 32 + d];
    }
    if (i < end) a0 += mean[(size_t)src[csr[i]] * 32 + d];
    h[(size_t)n * 32 + d] = a0 + a1;
}

// ---------------------------------------------------------------------------
// Stage 4a: g = h @ W^T  (node-level, [50K,32]@[32,32] — tiny).
// 32 node rows per block via LDS (stride 36 breaks bank aliasing).
// g may alias mean (mean is dead after k_node_h).
// ---------------------------------------------------------------------------
__global__ __launch_bounds__(256) void k_node_g(
    const float* __restrict__ h, const float* __restrict__ W,
    float* __restrict__ g)
{
    __shared__ float sh[32][36];
    const int t = threadIdx.x;
    const int n0 = blockIdx.x * 32;
    {
        int r  = t >> 3;
        int d4 = (t & 7) << 2;
        int n = n0 + r;
        float4 v = make_float4(0.f, 0.f, 0.f, 0.f);
        if (n < N_NODES) v = *(const float4*)(h + (size_t)n * 32 + d4);
        *(float4*)(&sh[r][d4]) = v;
    }
    __syncthreads();
    const int j  = t & 31;
    const int rb = t >> 5;
    float w[32];
#pragma unroll
    for (int k = 0; k < 8; ++k) {
        float4 wv = *(const float4*)(W + j * 32 + k * 4);
        w[4 * k + 0] = wv.x;
        w[4 * k + 1] = wv.y;
        w[4 * k + 2] = wv.z;
        w[4 * k + 3] = wv.w;
    }
    float a0 = 0.f, a1 = 0.f, a2 = 0.f, a3 = 0.f;
#pragma unroll
    for (int d = 0; d < 32; ++d) {
        float wd = w[d];
        a0 += sh[rb +  0][d] * wd;
        a1 += sh[rb +  8][d] * wd;
        a2 += sh[rb + 16][d] * wd;
        a3 += sh[rb + 24][d] * wd;
    }
    if (n0 + rb +  0 < N_NODES) g[(size_t)(n0 + rb +  0) * 32 + j] = a0;
    if (n0 + rb +  8 < N_NODES) g[(size_t)(n0 + rb +  8) * 32 + j] = a1;
    if (n0 + rb + 16 < N_NODES) g[(size_t)(n0 + rb + 16) * 32 + j] = a2;
    if (n0 + rb + 24 < N_NODES) g[(size_t)(n0 + rb + 24) * 32 + j] = a3;
}

// ---------------------------------------------------------------------------
// Stage 4b: out[e] = 0.5*(g[src]+g[dst]) + b. 8 lanes per edge (float4 per
// lane): g-row gathers are 128B-contiguous per edge, output store is
// perfectly coalesced (lane t writes bytes t*16).
// ---------------------------------------------------------------------------
__global__ __launch_bounds__(256) void k_edge_out2(
    const float* __restrict__ g, const int* __restrict__ src,
    const int* __restrict__ dst, const float* __restrict__ b,
    float* __restrict__ out, int E)
{
    int t = blockIdx.x * 256 + threadIdx.x;
    int e = t >> 3;
    if (e >= E) return;
    int d4 = (t & 7) << 2;
    int s = src[e];
    int n = dst[e];
    float4 a  = *(const float4*)(g + (size_t)s * 32 + d4);
    float4 c  = *(const float4*)(g + (size_t)n * 32 + d4);
    float4 bv = *(const float4*)(b + d4);
    float4 o;
    o.x = 0.5f * (a.x + c.x) + bv.x;
    o.y = 0.5f * (a.y + c.y) + bv.y;
    o.z = 0.5f * (a.z + c.z) + bv.z;
    o.w = 0.5f * (a.w + c.w) + bv.w;
    *(float4*)(out + (size_t)e * 32 + d4) = o;
}

extern "C" void kernel_launch(void* const* d_in, const int* in_sizes, int n_in,
                              void* d_out, int out_size, void* d_ws, size_t ws_size,
                              hipStream_t stream)
{
    const float* ef  = (const float*)d_in[0];
    const int*   src = (const int*)d_in[1];
    const int*   dst = (const int*)d_in[2];
    const float* W   = (const float*)d_in[3];
    const float* b   = (const float*)d_in[4];
    float*       out = (float*)d_out;
    const int E = in_sizes[1];

    // ---- workspace carve (all offsets 16B-aligned) ----
    const size_t NF = (size_t)N_NODES * 32;
    int*   cnt  = (int*)d_ws;            // N_NODES
    int*   off  = cnt + 50000;           // N_NODES+1 (padded to 50016)
    int*   cur  = off + 50016;           // N_NODES
    int*   csr  = cur + 50000;           // E
    float* mean = (float*)(csr + 1600000);  // NF floats
    float* h    = mean + NF;                // NF floats
    float* g    = mean;                     // alias: mean dead after k_node_h

    // zero only the histogram (ws is re-poisoned 0xAA before every launch)
    hipMemsetAsync(cnt, 0, (size_t)N_NODES * sizeof(int), stream);

    const int eblk = (E + 255) / 256;
    k_hist<<<eblk, 256, 0, stream>>>(dst, cnt, E);
    k_scan<<<1, SCAN_T, 0, stream>>>(cnt, off, cur, E);
    k_fill<<<eblk, 256, 0, stream>>>(dst, cur, csr, E);

    const int nblk = (N_NODES + 7) / 8;
    k_node_mean<<<nblk, 256, 0, stream>>>(ef, csr, off, mean);
    k_node_h<<<nblk, 256, 0, stream>>>(mean, src, csr, off, h);

    k_node_g<<<(N_NODES + 31) / 32, 256, 0, stream>>>(h, W, g);

    const int oblk = (E * 8 + 255) / 256;   // 12.8M threads
    k_edge_out2<<<oblk, 256, 0, stream>>>(g, src, dst, b, out, E);
}

// Round 3
// 589.066 us; speedup vs baseline: 1.6201x; 1.3805x over previous
//
#include <hip/hip_runtime.h>

#define N_NODES 50000
#define BSH 7                 // bucket = dst >> 7
#define BMASK 127
#define NBUCK 391             // ceil(50000/128)
#define EPB 4096              // edges per block in bucket hist/fill
#define CAPB 5120             // max edges per bucket (mean 4096, sigma ~64)

// ---------------------------------------------------------------------------
// A1: bucket histogram. LDS hist per block, one global atomic per (blk,bucket).
// ---------------------------------------------------------------------------
__global__ __launch_bounds__(256) void k_bhist(
    const int* __restrict__ dst, int* __restrict__ bcnt, int E)
{
    __shared__ int hist[NBUCK];
    for (int i = threadIdx.x; i < NBUCK; i += 256) hist[i] = 0;
    __syncthreads();
    int base = blockIdx.x * EPB;
    int lim  = min(base + EPB, E);
    for (int e = base + threadIdx.x; e < lim; e += 256)
        atomicAdd(&hist[dst[e] >> BSH], 1);
    __syncthreads();
    for (int i = threadIdx.x; i < NBUCK; i += 256)
        if (hist[i]) atomicAdd(&bcnt[i], hist[i]);
}

// ---------------------------------------------------------------------------
// A2: exclusive scan of 391 bucket counts. Cooperative load to LDS, serial
// scan by t0 in LDS (391 iters, ~cheap), cooperative store of off + cursors.
// ---------------------------------------------------------------------------
__global__ __launch_bounds__(512) void k_bscan(
    const int* __restrict__ bcnt, int* __restrict__ boff,
    int* __restrict__ bcur, int E)
{
    __shared__ int tmp[NBUCK];
    for (int i = threadIdx.x; i < NBUCK; i += 512) tmp[i] = bcnt[i];
    __syncthreads();
    if (threadIdx.x == 0) {
        int run = 0;
        for (int i = 0; i < NBUCK; ++i) { int c = tmp[i]; tmp[i] = run; run += c; }
    }
    __syncthreads();
    for (int i = threadIdx.x; i < NBUCK; i += 512) {
        boff[i] = tmp[i];
        bcur[i] = tmp[i];
    }
    if (threadIdx.x == 0) boff[NBUCK] = E;
}

// ---------------------------------------------------------------------------
// A3: bucketed fill. Stash dst (ushort) in LDS, LDS hist, grab per-block
// region base per bucket with ONE global atomic, then scatter packed words
// (e<<7)|(dst&127) — write runs are clustered, ~2x amp instead of 16x.
// ---------------------------------------------------------------------------
__global__ __launch_bounds__(256) void k_bfill(
    const int* __restrict__ dst, int* __restrict__ bcur,
    int* __restrict__ ebuf, int E)
{
    __shared__ unsigned short dstv[EPB];
    __shared__ int hist[NBUCK];
    __shared__ int basev[NBUCK];
    __shared__ int cur[NBUCK];
    for (int i = threadIdx.x; i < NBUCK; i += 256) hist[i] = 0;
    __syncthreads();
    int base = blockIdx.x * EPB;
    int lim  = min(base + EPB, E);
    for (int e = base + threadIdx.x; e < lim; e += 256) {
        int d = dst[e];
        dstv[e - base] = (unsigned short)d;
        atomicAdd(&hist[d >> BSH], 1);
    }
    __syncthreads();
    for (int i = threadIdx.x; i < NBUCK; i += 256) {
        int c = hist[i];
        cur[i] = 0;
        if (c) basev[i] = atomicAdd(&bcur[i], c);
    }
    __syncthreads();
    int n = lim - base;
    for (int idx = threadIdx.x; idx < n; idx += 256) {
        int d = (int)dstv[idx];
        int b = d >> BSH;
        int p = basev[b] + atomicAdd(&cur[b], 1);
        ebuf[p] = ((base + idx) << BSH) | (d & BMASK);
    }
}

// ---------------------------------------------------------------------------
// B: per-bucket LDS sort. One block per bucket; stage packed words in LDS,
// LDS hist over the 128 local nodes, serial LDS scan, LDS scatter, then
// IN-PLACE coalesced writeback of sorted edge ids (ebuf becomes csr) + off[].
// ---------------------------------------------------------------------------
__global__ __launch_bounds__(256) void k_bsort(
    int* __restrict__ ebuf, const int* __restrict__ boff,
    int* __restrict__ off, int E)
{
    __shared__ int stash[CAPB];
    __shared__ int sorted[CAPB];
    __shared__ int hist[128];
    __shared__ int loff[129];
    __shared__ int cur[128];
    const int b   = blockIdx.x;
    const int beg = boff[b];
    const int cnt = boff[b + 1] - beg;
    for (int i = threadIdx.x; i < 128; i += 256) hist[i] = 0;
    __syncthreads();
    for (int i = threadIdx.x; i < cnt; i += 256) {
        int w = ebuf[beg + i];
        stash[i] = w;
        atomicAdd(&hist[w & BMASK], 1);
    }
    __syncthreads();
    if (threadIdx.x == 0) {
        int run = 0;
        loff[0] = 0;
        for (int i = 0; i < 128; ++i) { run += hist[i]; loff[i + 1] = run; }
    }
    __syncthreads();
    for (int i = threadIdx.x; i < 128; i += 256) cur[i] = loff[i];
    __syncthreads();
    for (int i = threadIdx.x; i < cnt; i += 256) {
        int w = stash[i];
        int p = atomicAdd(&cur[w & BMASK], 1);
        sorted[p] = w >> BSH;                 // recover edge id
    }
    __syncthreads();
    for (int i = threadIdx.x; i < cnt; i += 256) ebuf[beg + i] = sorted[i];
    const int n0 = b << BSH;
    const int nn = min(128, N_NODES - n0);
    for (int j = threadIdx.x; j < nn; j += 256) off[n0 + j] = beg + loff[j];
    if (b == NBUCK - 1 && threadIdx.x == 0) off[N_NODES] = E;
}

// ---------------------------------------------------------------------------
// C1: mean[n] = sum of ef rows of n's in-edges / max(deg,1).
// 32 lanes per node, unroll x4 for 4 outstanding 128B row reads.
// ---------------------------------------------------------------------------
__global__ __launch_bounds__(256) void k_node_mean(
    const float* __restrict__ ef, const int* __restrict__ csr,
    const int* __restrict__ off, float* __restrict__ mean)
{
    int n = blockIdx.x * 8 + (threadIdx.x >> 5);
    if (n >= N_NODES) return;
    int d = threadIdx.x & 31;
    int beg = off[n], end = off[n + 1];
    float a0 = 0.f, a1 = 0.f, a2 = 0.f, a3 = 0.f;
    int i = beg;
    for (; i + 4 <= end; i += 4) {
        int e0 = csr[i], e1 = csr[i + 1], e2 = csr[i + 2], e3 = csr[i + 3];
        a0 += ef[(size_t)e0 * 32 + d];
        a1 += ef[(size_t)e1 * 32 + d];
        a2 += ef[(size_t)e2 * 32 + d];
        a3 += ef[(size_t)e3 * 32 + d];
    }
    for (; i < end; ++i) a0 += ef[(size_t)csr[i] * 32 + d];
    float s = (a0 + a1) + (a2 + a3);
    mean[(size_t)n * 32 + d] = s / fmaxf((float)(end - beg), 1.0f);
}

// ---------------------------------------------------------------------------
// C2: fused h + g. Per block: 32 nodes. Gather-reduce h rows into LDS
// (unroll x4), then 32x32 matmul g = h @ W^T, coalesced store of g.
// ---------------------------------------------------------------------------
__global__ __launch_bounds__(256) void k_node_hg(
    const float* __restrict__ mean, const int* __restrict__ src,
    const int* __restrict__ csr, const int* __restrict__ off,
    const float* __restrict__ W, float* __restrict__ g)
{
    __shared__ float sh[32][36];
    const int t   = threadIdx.x;
    const int d   = t & 31;
    const int grp = t >> 5;          // 0..7
    const int n0  = blockIdx.x * 32;
#pragma unroll
    for (int r = 0; r < 4; ++r) {
        int n = n0 + r * 8 + grp;
        float a0 = 0.f, a1 = 0.f, a2 = 0.f, a3 = 0.f;
        if (n < N_NODES) {
            int beg = off[n], end = off[n + 1];
            int i = beg;
            for (; i + 4 <= end; i += 4) {
                int s0 = src[csr[i]];
                int s1 = src[csr[i + 1]];
                int s2 = src[csr[i + 2]];
                int s3 = src[csr[i + 3]];
                a0 += mean[(size_t)s0 * 32 + d];
                a1 += mean[(size_t)s1 * 32 + d];
                a2 += mean[(size_t)s2 * 32 + d];
                a3 += mean[(size_t)s3 * 32 + d];
            }
            for (; i < end; ++i) a0 += mean[(size_t)src[csr[i]] * 32 + d];
        }
        sh[r * 8 + grp][d] = (a0 + a1) + (a2 + a3);
    }
    __syncthreads();
    // ---- g = h @ W^T for these 32 nodes
    const int j  = t & 31;
    const int rb = t >> 5;
    float w[32];
#pragma unroll
    for (int k = 0; k < 8; ++k) {
        float4 wv = *(const float4*)(W + j * 32 + k * 4);
        w[4 * k + 0] = wv.x;
        w[4 * k + 1] = wv.y;
        w[4 * k + 2] = wv.z;
        w[4 * k + 3] = wv.w;
    }
    float a0 = 0.f, a1 = 0.f, a2 = 0.f, a3 = 0.f;
#pragma unroll
    for (int dd = 0; dd < 32; ++dd) {
        float wd = w[dd];
        a0 += sh[rb +  0][dd] * wd;
        a1 += sh[rb +  8][dd] * wd;
        a2 += sh[rb + 16][dd] * wd;
        a3 += sh[rb + 24][dd] * wd;
    }
    if (n0 + rb +  0 < N_NODES) g[(size_t)(n0 + rb +  0) * 32 + j] = a0;
    if (n0 + rb +  8 < N_NODES) g[(size_t)(n0 + rb +  8) * 32 + j] = a1;
    if (n0 + rb + 16 < N_NODES) g[(size_t)(n0 + rb + 16) * 32 + j] = a2;
    if (n0 + rb + 24 < N_NODES) g[(size_t)(n0 + rb + 24) * 32 + j] = a3;
}

// ---------------------------------------------------------------------------
// C3: out[e] = 0.5*(g[src]+g[dst]) + b. 8 lanes x float4 per edge;
// fully coalesced 128B output runs.
// ---------------------------------------------------------------------------
__global__ __launch_bounds__(256) void k_edge_out2(
    const float* __restrict__ g, const int* __restrict__ src,
    const int* __restrict__ dst, const float* __restrict__ b,
    float* __restrict__ out, int E)
{
    int t = blockIdx.x * 256 + threadIdx.x;
    int e = t >> 3;
    if (e >= E) return;
    int d4 = (t & 7) << 2;
    int s = src[e];
    int n = dst[e];
    float4 a  = *(const float4*)(g + (size_t)s * 32 + d4);
    float4 c  = *(const float4*)(g + (size_t)n * 32 + d4);
    float4 bv = *(const float4*)(b + d4);
    float4 o;
    o.x = 0.5f * (a.x + c.x) + bv.x;
    o.y = 0.5f * (a.y + c.y) + bv.y;
    o.z = 0.5f * (a.z + c.z) + bv.z;
    o.w = 0.5f * (a.w + c.w) + bv.w;
    *(float4*)(out + (size_t)e * 32 + d4) = o;
}

extern "C" void kernel_launch(void* const* d_in, const int* in_sizes, int n_in,
                              void* d_out, int out_size, void* d_ws, size_t ws_size,
                              hipStream_t stream)
{
    const float* ef  = (const float*)d_in[0];
    const int*   src = (const int*)d_in[1];
    const int*   dst = (const int*)d_in[2];
    const float* W   = (const float*)d_in[3];
    const float* b   = (const float*)d_in[4];
    float*       out = (float*)d_out;
    const int E = in_sizes[1];

    // ---- workspace carve (16B-aligned chunks) ----
    int*   bcnt = (int*)d_ws;          // NBUCK (pad 512)
    int*   boff = bcnt + 512;          // NBUCK+1 (pad 512)
    int*   bcur = boff + 512;          // NBUCK (pad 512)
    int*   off  = bcur + 512;          // N_NODES+1 (pad 50016)
    int*   csr  = off + 50016;         // E (ebuf -> sorted in place by k_bsort)
    float* mean = (float*)(csr + E);   // N*32 floats
    float* g    = mean + (size_t)N_NODES * 32;  // N*32 floats

    hipMemsetAsync(bcnt, 0, 512 * sizeof(int), stream);

    const int abk = (E + EPB - 1) / EPB;   // 391
    k_bhist<<<abk, 256, 0, stream>>>(dst, bcnt, E);
    k_bscan<<<1, 512, 0, stream>>>(bcnt, boff, bcur, E);
    k_bfill<<<abk, 256, 0, stream>>>(dst, bcur, csr, E);
    k_bsort<<<NBUCK, 256, 0, stream>>>(csr, boff, off, E);

    k_node_mean<<<(N_NODES + 7) / 8, 256, 0, stream>>>(ef, csr, off, mean);
    k_node_hg<<<(N_NODES + 31) / 32, 256, 0, stream>>>(mean, src, csr, off, W, g);

    const int oblk = (E * 8 + 255) / 256;
    k_edge_out2<<<oblk, 256, 0, stream>>>(g, src, dst, b, out, E);
}